// Round 1
// baseline (618.174 us; speedup 1.0000x reference)
//
#include <hip/hip_runtime.h>
#include <hip/hip_bf16.h>

// Problem constants (fixed by the reference)
#define BB 4
#define SS 2048
#define DIN 4096
#define DOUT 4096
#define BLKC 256
#define MM (BB * SS)        // 8192
#define NN DOUT             // 4096
#define KK DIN              // 4096

typedef __attribute__((ext_vector_type(8))) short short8;
typedef __attribute__((ext_vector_type(4))) float f32x4;

__device__ static inline unsigned short bf16rne(float f) {
    unsigned int u = __float_as_uint(f);
    u += 0x7FFF + ((u >> 16) & 1);
    return (unsigned short)(u >> 16);
}

__device__ static inline void gload_lds16(const void* g, void* l) {
    __builtin_amdgcn_global_load_lds(
        (const __attribute__((address_space(1))) void*)g,
        (__attribute__((address_space(3))) void*)l, 16, 0, 0);
}

// ---------------- kernel 1: x fp32 -> bf16 ----------------
__global__ __launch_bounds__(256) void cvt_x_bf16(const float* __restrict__ x,
                                                  unsigned short* __restrict__ xb) {
    const int idx = blockIdx.x * 256 + threadIdx.x;   // one thread = 8 elems
    const size_t i8 = (size_t)idx * 8;
    float4 v0 = *(const float4*)(x + i8);
    float4 v1 = *(const float4*)(x + i8 + 4);
    short8 o;
    o[0] = (short)bf16rne(v0.x); o[1] = (short)bf16rne(v0.y);
    o[2] = (short)bf16rne(v0.z); o[3] = (short)bf16rne(v0.w);
    o[4] = (short)bf16rne(v1.x); o[5] = (short)bf16rne(v1.y);
    o[6] = (short)bf16rne(v1.z); o[7] = (short)bf16rne(v1.w);
    *(short8*)(xb + i8) = o;
}

// ---------------- kernel 2: W_eff = W + circulant(k)/DIN -> bf16 ----------------
__global__ __launch_bounds__(256) void build_weff(const float* __restrict__ W,
                                                  const float* __restrict__ k3,
                                                  unsigned short* __restrict__ Wb) {
    const int idx = blockIdx.x * 256 + threadIdx.x;   // one thread = 8 elems
    const size_t i8 = (size_t)idx * 8;
    const int o = (int)(i8 >> 12);        // row in [0,4096)
    const int i = (int)(i8 & 4095);       // col base
    const int p = o >> 8, t = o & 255;
    const int q = i >> 8, s0 = i & 255;   // 8 consecutive s, no block crossing (i8 % 8 == 0)
    const float* kr = k3 + (((p << 4) + q) << 8);
    float4 w0 = *(const float4*)(W + i8);
    float4 w1 = *(const float4*)(W + i8 + 4);
    float v[8] = {w0.x, w0.y, w0.z, w0.w, w1.x, w1.y, w1.z, w1.w};
    short8 out;
    const float inv = 1.0f / (float)DIN;
#pragma unroll
    for (int j = 0; j < 8; ++j) {
        const int kidx = (t - (s0 + j)) & 255;
        out[j] = (short)bf16rne(v[j] + kr[kidx] * inv);
    }
    *(short8*)(Wb + i8) = out;
}

// ---------------- kernel 3: C = A(bf16) @ Wb(bf16)^T + bias (m97-style 128^2) ----------------
__global__ __launch_bounds__(256, 2) void gemm_bt(const unsigned short* __restrict__ A,
                                                  const unsigned short* __restrict__ Bw,
                                                  const float* __restrict__ bias,
                                                  float* __restrict__ C) {
    __shared__ unsigned short ldsA[128 * 32];
    __shared__ unsigned short ldsB[128 * 32];

    const int tid = threadIdx.x;
    const int nwg = (MM / 128) * (NN / 128);          // 2048, % 8 == 0
    const int bid = blockIdx.x;
    const int swz = (bid & 7) * (nwg >> 3) + (bid >> 3);   // XCD-bijective swizzle
    const int bm = swz >> 5;                          // NN/128 = 32 -> 5 bits
    const int bn = swz & 31;
    const int m0 = bm * 128, n0 = bn * 128;

    const int l = tid & 63, w = tid >> 6;
    const int wm = (w >> 1) * 64, wn = (w & 1) * 64;  // wave's 64x64 sub-tile
    const int lr = l & 15;                            // fragment row (M or N side)
    const int lk = (l >> 4) * 8;                      // fragment k offset

    // staging geometry: round r covers rows r*64 + tid/4, 16B chunk (tid%4)*8 elems
    const int rowA = tid >> 2;
    const int col8 = (tid & 3) * 8;
    const unsigned short* gA = A + (size_t)(m0 + rowA) * KK + col8;
    const unsigned short* gB = Bw + (size_t)(n0 + rowA) * KK + col8;
    unsigned short* lA = &ldsA[tid * 8];
    unsigned short* lB = &ldsB[tid * 8];

    f32x4 acc[4][4];
#pragma unroll
    for (int i = 0; i < 4; ++i)
#pragma unroll
        for (int j = 0; j < 4; ++j) acc[i][j] = (f32x4){0.f, 0.f, 0.f, 0.f};

    for (int kt = 0; kt < KK; kt += 32) {
        // stage A tile (128x32 bf16, 2 rounds) + B tile (2 rounds), lane-linear LDS dest
        gload_lds16(gA + kt, lA);
        gload_lds16(gA + (size_t)64 * KK + kt, lA + 64 * 32);
        gload_lds16(gB + kt, lB);
        gload_lds16(gB + (size_t)64 * KK + kt, lB + 64 * 32);
        __syncthreads();

        short8 af[4], bf[4];
#pragma unroll
        for (int mi = 0; mi < 4; ++mi)
            af[mi] = *(const short8*)&ldsA[(wm + mi * 16 + lr) * 32 + lk];
#pragma unroll
        for (int ni = 0; ni < 4; ++ni)
            bf[ni] = *(const short8*)&ldsB[(wn + ni * 16 + lr) * 32 + lk];
#pragma unroll
        for (int mi = 0; mi < 4; ++mi)
#pragma unroll
            for (int ni = 0; ni < 4; ++ni)
                acc[mi][ni] = __builtin_amdgcn_mfma_f32_16x16x32_bf16(
                    af[mi], bf[ni], acc[mi][ni], 0, 0, 0);
        __syncthreads();
    }

    // epilogue: C[m][n] = acc + bias[n]; D layout: col = lane&15, row = (lane>>4)*4 + reg
#pragma unroll
    for (int ni = 0; ni < 4; ++ni) {
        const int n = n0 + wn + ni * 16 + lr;
        const float bv = bias[n];
#pragma unroll
        for (int mi = 0; mi < 4; ++mi) {
            const int mbase = m0 + wm + mi * 16 + (l >> 4) * 4;
#pragma unroll
            for (int r = 0; r < 4; ++r)
                C[(size_t)(mbase + r) * NN + n] = acc[mi][ni][r] + bv;
        }
    }
}

extern "C" void kernel_launch(void* const* d_in, const int* in_sizes, int n_in,
                              void* d_out, int out_size, void* d_ws, size_t ws_size,
                              hipStream_t stream) {
    const float* x    = (const float*)d_in[0];  // (4, 2048, 4096)
    const float* W    = (const float*)d_in[1];  // (4096, 4096)
    const float* bias = (const float*)d_in[2];  // (4096,)
    const float* k3   = (const float*)d_in[3];  // (16, 16, 256)
    float* out = (float*)d_out;                 // (4, 2048, 4096)

    unsigned short* xb = (unsigned short*)d_ws;                                   // 64 MB
    unsigned short* Wb = (unsigned short*)((char*)d_ws + (size_t)64 * 1024 * 1024); // 32 MB

    cvt_x_bf16<<<(MM * KK) / (256 * 8), 256, 0, stream>>>(x, xb);
    build_weff<<<(NN * KK) / (256 * 8), 256, 0, stream>>>(W, k3, Wb);
    gemm_bt<<<(MM / 128) * (NN / 128), 256, 0, stream>>>(xb, Wb, bias, out);
}

// Round 2
// 534.515 us; speedup vs baseline: 1.1565x; 1.1565x over previous
//
#include <hip/hip_runtime.h>
#include <hip/hip_bf16.h>

#define MM 8192
#define NN 4096
#define KK 4096
#define BKT 32            // K per LDS tile
#define NT (KK / BKT)     // 128 K-tiles

typedef unsigned short u16;
typedef __attribute__((ext_vector_type(8))) short short8;
typedef __attribute__((ext_vector_type(4))) float f32x4;

__device__ static inline u16 bf16rne(float f) {
    unsigned int u = __float_as_uint(f);
    u += 0x7FFF + ((u >> 16) & 1);
    return (u16)(u >> 16);
}

__device__ static inline void gload_lds16(const void* g, void* l) {
    __builtin_amdgcn_global_load_lds(
        (const __attribute__((address_space(1))) void*)g,
        (__attribute__((address_space(3))) void*)l, 16, 0, 0);
}

// ---------------- fused prep: x->bf16  and  W_eff = W + circulant(k)/DIN -> bf16 ----------------
#define CVT_BLOCKS ((MM * KK) / (256 * 8))   // 16384
#define WEF_BLOCKS ((NN * KK) / (256 * 8))   // 8192

__global__ __launch_bounds__(256) void prep(const float* __restrict__ x,
                                            const float* __restrict__ W,
                                            const float* __restrict__ k3,
                                            u16* __restrict__ xb,
                                            u16* __restrict__ Wb) {
    const int bx = blockIdx.x;
    if (bx < CVT_BLOCKS) {
        const int idx = bx * 256 + threadIdx.x;
        const size_t i8 = (size_t)idx * 8;
        float4 v0 = *(const float4*)(x + i8);
        float4 v1 = *(const float4*)(x + i8 + 4);
        short8 o;
        o[0] = (short)bf16rne(v0.x); o[1] = (short)bf16rne(v0.y);
        o[2] = (short)bf16rne(v0.z); o[3] = (short)bf16rne(v0.w);
        o[4] = (short)bf16rne(v1.x); o[5] = (short)bf16rne(v1.y);
        o[6] = (short)bf16rne(v1.z); o[7] = (short)bf16rne(v1.w);
        *(short8*)(xb + i8) = o;
    } else {
        const int idx = (bx - CVT_BLOCKS) * 256 + threadIdx.x;
        const size_t i8 = (size_t)idx * 8;
        const int o = (int)(i8 >> 12);        // row in [0,4096)
        const int i = (int)(i8 & 4095);       // col base
        const int p = o >> 8, t = o & 255;
        const int q = i >> 8, s0 = i & 255;
        const float* kr = k3 + (((p << 4) + q) << 8);
        float4 w0 = *(const float4*)(W + i8);
        float4 w1 = *(const float4*)(W + i8 + 4);
        float v[8] = {w0.x, w0.y, w0.z, w0.w, w1.x, w1.y, w1.z, w1.w};
        short8 out;
        const float inv = 1.0f / (float)KK;
#pragma unroll
        for (int j = 0; j < 8; ++j) {
            const int kidx = (t - (s0 + j)) & 255;
            out[j] = (short)bf16rne(v[j] + kr[kidx] * inv);
        }
        *(short8*)(Wb + i8) = out;
    }
}

// ---------------- gemm: 256x256 tile, BK=32, 4-deep LDS pipeline, counted vmcnt ----------------
__global__ __launch_bounds__(512, 2) void gemm_bt(const u16* __restrict__ A,
                                                  const u16* __restrict__ Bw,
                                                  const float* __restrict__ bias,
                                                  float* __restrict__ C) {
    __shared__ u16 lA[4][256 * BKT];   // 4 x 16 KB
    __shared__ u16 lB[4][256 * BKT];   // 4 x 16 KB   (128 KB total)

    const int tid = threadIdx.x;
    const int bid = blockIdx.x;
    const int nwg = (MM / 256) * (NN / 256);           // 512, % 8 == 0
    const int swz = (bid & 7) * (nwg >> 3) + (bid >> 3);
    const int m0 = (swz >> 4) * 256;                   // NN/256 = 16 col-panels
    const int n0 = (swz & 15) * 256;

    const int l = tid & 63;
    const int wid = tid >> 6;
    const int wr = wid >> 2, wc = wid & 3;             // wave = 128(M) x 64(N)

    const int lr = l & 15;
    // read-side swizzled k-slot: (l>>4) ^ f(row), f(row) = (row&3)^((row>>2)&3) = (l&3)^((l>>2)&3)
    const int ks8 = ((((l >> 4) ^ (l & 3) ^ ((l >> 2) & 3)) & 3)) * 8;

    // staging: thread covers row (i0*128 + tid>>2), 16B slot (tid&3), pre-swizzled global source
    const int srow = tid >> 2;
    const int fst = ((tid >> 2) ^ (tid >> 4)) & 3;
    const int sslot = ((tid & 3) ^ fst) * 8;
    const u16* gA0 = A  + (size_t)(m0 + srow) * KK + sslot;
    const u16* gB0 = Bw + (size_t)(n0 + srow) * KK + sslot;

#define STAGE_A(t)  do { const u16* g_ = gA0 + (t) * BKT; \
        gload_lds16(g_, &lA[(t) & 3][tid * 8]); \
        gload_lds16(g_ + (size_t)128 * KK, &lA[(t) & 3][4096 + tid * 8]); } while (0)
#define STAGE_B(t)  do { const u16* g_ = gB0 + (t) * BKT; \
        gload_lds16(g_, &lB[(t) & 3][tid * 8]); \
        gload_lds16(g_ + (size_t)128 * KK, &lB[(t) & 3][4096 + tid * 8]); } while (0)

    f32x4 acc[8][4];
#pragma unroll
    for (int i = 0; i < 8; ++i)
#pragma unroll
        for (int j = 0; j < 4; ++j) acc[i][j] = (f32x4){0.f, 0.f, 0.f, 0.f};

    // prologue: stage tiles 0,1,2 (12 loads); tile 0 landed when <=8 outstanding
    STAGE_A(0); STAGE_B(0);
    STAGE_A(1); STAGE_B(1);
    STAGE_A(2); STAGE_B(2);
    asm volatile("s_waitcnt vmcnt(8)" ::: "memory");
    __builtin_amdgcn_s_barrier();
    asm volatile("" ::: "memory");

    const int arow = wr * 128 + lr;
    const int brow = wc * 64 + lr;

    for (int t = 0; t < NT; ++t) {
        const u16* bufA = lA[t & 3];
        const u16* bufB = lB[t & 3];

        // phase A: m-frags 0..3 + all B frags
        short8 a0[4], b0[4];
#pragma unroll
        for (int i = 0; i < 4; ++i)
            a0[i] = *(const short8*)&bufA[(arow + i * 16) * BKT + ks8];
#pragma unroll
        for (int j = 0; j < 4; ++j)
            b0[j] = *(const short8*)&bufB[(brow + j * 16) * BKT + ks8];
        if (t + 3 < NT) STAGE_A(t + 3);
        __builtin_amdgcn_s_setprio(1);
#pragma unroll
        for (int i = 0; i < 4; ++i)
#pragma unroll
            for (int j = 0; j < 4; ++j)
                acc[i][j] = __builtin_amdgcn_mfma_f32_16x16x32_bf16(a0[i], b0[j], acc[i][j], 0, 0, 0);
        __builtin_amdgcn_s_setprio(0);

        // phase B: m-frags 4..7, reuse B frags
        short8 a1[4];
#pragma unroll
        for (int i = 0; i < 4; ++i)
            a1[i] = *(const short8*)&bufA[(arow + 64 + i * 16) * BKT + ks8];
        if (t + 3 < NT) STAGE_B(t + 3);
        __builtin_amdgcn_s_setprio(1);
#pragma unroll
        for (int i = 0; i < 4; ++i)
#pragma unroll
            for (int j = 0; j < 4; ++j)
                acc[4 + i][j] = __builtin_amdgcn_mfma_f32_16x16x32_bf16(a1[i], b0[j], acc[4 + i][j], 0, 0, 0);
        __builtin_amdgcn_s_setprio(0);

        // counted wait: tiles t+2, t+3 (8 loads) may stay in flight; tile t+1 landed
        asm volatile("s_waitcnt vmcnt(8)" ::: "memory");
        __builtin_amdgcn_s_barrier();
        asm volatile("" ::: "memory");
    }

    // epilogue: C[m][n] = acc + bias[n]; D frag: col = lane&15, row = (lane>>4)*4 + reg
    const int crow0 = m0 + wr * 128 + (l >> 4) * 4;
    const int ccol0 = n0 + wc * 64 + lr;
#pragma unroll
    for (int j = 0; j < 4; ++j) {
        const int n = ccol0 + j * 16;
        const float bv = bias[n];
#pragma unroll
        for (int i = 0; i < 8; ++i) {
            const int mb = crow0 + i * 16;
#pragma unroll
            for (int r = 0; r < 4; ++r)
                C[(size_t)(mb + r) * NN + n] = acc[i][j][r] + bv;
        }
    }
#undef STAGE_A
#undef STAGE_B
}

extern "C" void kernel_launch(void* const* d_in, const int* in_sizes, int n_in,
                              void* d_out, int out_size, void* d_ws, size_t ws_size,
                              hipStream_t stream) {
    const float* x    = (const float*)d_in[0];  // (4, 2048, 4096)
    const float* W    = (const float*)d_in[1];  // (4096, 4096)
    const float* bias = (const float*)d_in[2];  // (4096,)
    const float* k3   = (const float*)d_in[3];  // (16, 16, 256)
    float* out = (float*)d_out;                 // (4, 2048, 4096)

    u16* xb = (u16*)d_ws;                                        // 64 MB
    u16* Wb = (u16*)((char*)d_ws + (size_t)64 * 1024 * 1024);    // 32 MB

    prep<<<CVT_BLOCKS + WEF_BLOCKS, 256, 0, stream>>>(x, W, k3, xb, Wb);
    gemm_bt<<<(MM / 256) * (NN / 256), 512, 0, stream>>>(xb, Wb, bias, out);
}